// Round 4
// baseline (5076.814 us; speedup 1.0000x reference)
//
#include <hip/hip_runtime.h>
#include <math.h>

#define TSTEPS 48
#define NCELL 32
#define ND 224
#define NBLK (NCELL + ND)

// ---------------- ws float offsets ----------------
#define OFF_W0T   0            // [2 hh][128 k4][512 gc] float4 (Wih0 re-layout)
#define OFF_W1T   524288       // [2][64][512] float4 (Wih1)
#define OFF_WH0T  786432       // [2][64][512] float4 (Whh0)
#define OFF_WH1T  1048576      // [2][64][512] float4 (Whh1)
#define OFF_BS0   1310720      // [2 hh][512 gc]
#define OFF_BS1   1311744
#define OFF_HINIT 1312768      // [64][256]
#define OFF_CINIT 1329152
#define OFF_H0BUF 1345536      // [64][256]
#define OFF_H1BUF 1361920
#define OFF_FLOAT_END 1378304
// then: key2 u64[64][256] (131072 B), flags u32[12288] (49152 B)

#define FSTR 32
#define FL_H0F   0       // 32
#define FL_H1C   1024    // 32
#define FL_H1ALL 2048    // 32
#define FL_DFLAG 3072    // 224
#define FL_DMIR  10240   // 32
#define FL_TOK   11264   // 32
#define NFLAGU32 12288

typedef float f4v __attribute__((ext_vector_type(4)));

// ---- coherent accessors ----
__device__ __forceinline__ unsigned ld_cohu(const unsigned* p) {
  return __hip_atomic_load((unsigned*)p, __ATOMIC_RELAXED, __HIP_MEMORY_SCOPE_AGENT);
}
__device__ __forceinline__ void st_cohu(unsigned* p, unsigned v) {
  __hip_atomic_store(p, v, __ATOMIC_RELAXED, __HIP_MEMORY_SCOPE_AGENT);
}
__device__ __forceinline__ unsigned long long ld_coh64(const unsigned long long* p) {
  return __hip_atomic_load((unsigned long long*)p, __ATOMIC_RELAXED, __HIP_MEMORY_SCOPE_AGENT);
}
__device__ __forceinline__ void st_coh64(unsigned long long* p, unsigned long long v) {
  __hip_atomic_store(p, v, __ATOMIC_RELAXED, __HIP_MEMORY_SCOPE_AGENT);
}
// 16B coherent load (bypass L0+L2 -> IC), blocking
__device__ __forceinline__ float4 ldg_coh_f4(const float4* p) {
  f4v r;
  asm volatile("global_load_dwordx4 %0, %1, off sc0 sc1\n\ts_waitcnt vmcnt(0)"
               : "=v"(r) : "v"(p) : "memory");
  return make_float4(r.x, r.y, r.z, r.w);
}
// 4 x 16B coherent loads in flight, one wait
__device__ __forceinline__ void ldg_coh_f4x4(const float4* p0, const float4* p1,
                                             const float4* p2, const float4* p3,
                                             float4& a, float4& b, float4& c, float4& d) {
  f4v ra, rb, rc, rd;
  asm volatile(
      "global_load_dwordx4 %0, %4, off sc0 sc1\n\t"
      "global_load_dwordx4 %1, %5, off sc0 sc1\n\t"
      "global_load_dwordx4 %2, %6, off sc0 sc1\n\t"
      "global_load_dwordx4 %3, %7, off sc0 sc1\n\t"
      "s_waitcnt vmcnt(0)"
      : "=&v"(ra), "=&v"(rb), "=&v"(rc), "=&v"(rd)
      : "v"(p0), "v"(p1), "v"(p2), "v"(p3) : "memory");
  a = make_float4(ra.x, ra.y, ra.z, ra.w);
  b = make_float4(rb.x, rb.y, rb.z, rb.w);
  c = make_float4(rc.x, rc.y, rc.z, rc.w);
  d = make_float4(rd.x, rd.y, rd.z, rd.w);
}
// 16B coherent write-through store (fire and forget; drain_vm before flag post)
__device__ __forceinline__ void stg_coh_f4(float4* p, float4 v) {
  f4v t = {v.x, v.y, v.z, v.w};
  asm volatile("global_store_dwordx4 %0, %1, off sc0 sc1" :: "v"(p), "v"(t) : "memory");
}
__device__ __forceinline__ void drain_vm() {
  asm volatile("s_waitcnt vmcnt(0)" ::: "memory");
}
// non-temporal 16B load (streaming; don't pollute L2 — protects cell weights in L2)
__device__ __forceinline__ float4 ldnt_f4(const float4* p) {
  f4v v = __builtin_nontemporal_load((const f4v*)p);
  return make_float4(v.x, v.y, v.z, v.w);
}
__device__ __forceinline__ float sigf(float x) { return 1.0f / (1.0f + expf(-x)); }
__device__ __forceinline__ unsigned long long u64max(unsigned long long a, unsigned long long b) {
  return a > b ? a : b;
}
__device__ __forceinline__ unsigned long long wmax64(unsigned long long k) {
#pragma unroll
  for (int off = 1; off < 64; off <<= 1) {
    unsigned long long o = __shfl_xor(k, off, 64);
    k = u64max(k, o);
  }
  return k;
}
__device__ __forceinline__ unsigned long long packkey(float lg, int v) {
  unsigned u = __float_as_uint(lg);
  u = (u & 0x80000000u) ? ~u : (u | 0x80000000u);
  return ((unsigned long long)u << 32) | (unsigned)(~(unsigned)v);
}
__device__ __forceinline__ float4 f4add(float4 a, float4 b) {
  return make_float4(a.x + b.x, a.y + b.y, a.z + b.z, a.w + b.w);
}

// ---------------- init kernels ----------------
__global__ void lstm_init_kernel(const float* enc, const float* Wh, const float* bh,
                                 const float* Wc, const float* bc,
                                 const float* bih0, const float* bhh0,
                                 const float* bih1, const float* bhh1,
                                 float* ws, unsigned long long* key2, unsigned* flags) {
  const int tid = threadIdx.x, blk = blockIdx.x;
  if (blk < 64) {
    __shared__ float el[256];
    el[tid] = enc[blk * 256 + tid];
    __syncthreads();
    const float4* el4 = (const float4*)el;
    const float4* wh4 = (const float4*)(Wh + tid * 256);
    const float4* wc4 = (const float4*)(Wc + tid * 256);
    float ah = bh[tid], ac = bc[tid];
#pragma unroll 4
    for (int f = 0; f < 64; ++f) {
      float4 x = el4[f], a = wh4[f], b = wc4[f];
      ah = fmaf(a.x, x.x, fmaf(a.y, x.y, fmaf(a.z, x.z, fmaf(a.w, x.w, ah))));
      ac = fmaf(b.x, x.x, fmaf(b.y, x.y, fmaf(b.z, x.z, fmaf(b.w, x.w, ac))));
    }
    ws[OFF_HINIT + blk * 256 + tid] = ah;
    ws[OFF_CINIT + blk * 256 + tid] = ac;
  } else if (blk == 64) {
    for (int g = tid; g < 1024; g += 256) {
      int hh = g >> 9, gc = g & 511;
      int row = (gc >> 7) * 256 + hh * 128 + (gc & 127);
      ws[OFF_BS0 + g] = bih0[row] + bhh0[row];
      ws[OFF_BS1 + g] = bih1[row] + bhh1[row];
    }
  } else {
    const int base = (blk - 65) * 256 + tid;  // 15 blocks, stride 3840
    for (int i = base; i < 64 * 256; i += 15 * 256) key2[i] = 0ull;
    for (int i = base; i < NFLAGU32; i += 15 * 256) flags[i] = 0u;
  }
}

// re-layout the 4 gate-weight matrices into [hh][k4][512 gc] float4
__global__ void lstm_relayout_kernel(const float* Wih0, const float* Whh0,
                                     const float* Wih1, const float* Whh1, float* ws) {
  const int gid = blockIdx.x * 256 + threadIdx.x;
  const int gstr = 256 * 256;
  const float* srcs[4] = {Wih0, Wih1, Whh0, Whh1};
  const int dsts[4] = {OFF_W0T, OFF_W1T, OFF_WH0T, OFF_WH1T};
  const int k4tot[4] = {128, 64, 64, 64};
  for (int s = 0; s < 4; ++s) {
    const int n = 2 * k4tot[s] * 512;
    float4* dst = (float4*)(ws + dsts[s]);
    const float4* src = (const float4*)srcs[s];
    for (int e = gid; e < n; e += gstr) {
      int hh = e / (k4tot[s] * 512);
      int r = e - hh * k4tot[s] * 512;
      int k4 = r / 512, gc = r - k4 * 512;
      int row = (gc >> 7) * 256 + hh * 128 + (gc & 127);
      dst[e] = src[(size_t)row * k4tot[s] + k4];
    }
  }
}

// ---------------- decode: shared-memory layouts ----------------
struct CellSm {
  float x[4 * 512];
  float4 part[1024];
  float4 r0res[512];
  float4 r1res[512];
  float h0[4 * 256];
  float h1[4 * 256];
  float c0[4 * 128];
  float c1[4 * 128];
  int tok[4];
  unsigned fm[32];
  unsigned long long fred[16];
  int done4;
  int alldone;
};
struct DSm {
  float w[16 * 144 * 4];        // [k4][144 rows][4]
  float h[64 * 68];             // [b][68] (padded, 16B-aligned rows)
  unsigned long long kr[128];   // [batch] folded keys (64 used)
};
union Smem { CellSm c; DSm d; };

// GEMV, 2 output rows per thread (rows p and p+256), 512 active threads.
// Halves the per-wave x-broadcast LDS issues vs 1-row/1024-thread version.
// part layout identical to before: [kh 2][gc 512] float4 (4 batches).
template <int K4H>
__device__ __forceinline__ void gemv_two(const float4* __restrict__ W,
                                         const float* __restrict__ xl, int xstride,
                                         float4* __restrict__ part, int tid) {
  if (tid < 512) {
    const int kh = tid >> 8;       // k-half
    const int p = tid & 255;       // row pair index: rows p, p+256
    float a0 = 0.f, a1 = 0.f, a2 = 0.f, a3 = 0.f;
    float b0 = 0.f, b1 = 0.f, b2 = 0.f, b3 = 0.f;
    const float4* wp0 = W + (size_t)(kh * K4H) * 512 + p;
    const float4* wp1 = wp0 + 256;
    const float* x0 = xl + kh * K4H * 4;
#pragma unroll 8
    for (int i = 0; i < K4H; ++i) {
      float4 w0 = wp0[(size_t)i * 512];
      float4 w1 = wp1[(size_t)i * 512];
      float4 xa = *(const float4*)(x0 + i * 4);
      float4 xb = *(const float4*)(x0 + xstride + i * 4);
      float4 xc = *(const float4*)(x0 + 2 * xstride + i * 4);
      float4 xd = *(const float4*)(x0 + 3 * xstride + i * 4);
      a0 = fmaf(w0.x, xa.x, fmaf(w0.y, xa.y, fmaf(w0.z, xa.z, fmaf(w0.w, xa.w, a0))));
      a1 = fmaf(w0.x, xb.x, fmaf(w0.y, xb.y, fmaf(w0.z, xb.z, fmaf(w0.w, xb.w, a1))));
      a2 = fmaf(w0.x, xc.x, fmaf(w0.y, xc.y, fmaf(w0.z, xc.z, fmaf(w0.w, xc.w, a2))));
      a3 = fmaf(w0.x, xd.x, fmaf(w0.y, xd.y, fmaf(w0.z, xd.z, fmaf(w0.w, xd.w, a3))));
      b0 = fmaf(w1.x, xa.x, fmaf(w1.y, xa.y, fmaf(w1.z, xa.z, fmaf(w1.w, xa.w, b0))));
      b1 = fmaf(w1.x, xb.x, fmaf(w1.y, xb.y, fmaf(w1.z, xb.z, fmaf(w1.w, xb.w, b1))));
      b2 = fmaf(w1.x, xc.x, fmaf(w1.y, xc.y, fmaf(w1.z, xc.z, fmaf(w1.w, xc.w, b2))));
      b3 = fmaf(w1.x, xd.x, fmaf(w1.y, xd.y, fmaf(w1.z, xd.z, fmaf(w1.w, xd.w, b3))));
    }
    part[kh * 512 + p] = make_float4(a0, a1, a2, a3);
    part[kh * 512 + p + 256] = make_float4(b0, b1, b2, b3);
  }
}

__device__ __forceinline__ void cellfold(const float4* part, const float4* rres,
                                         const float* bs, float* cst, float* hst,
                                         int hh, int tid) {
  if (tid < 512) {
    int jj = tid & 127, b = tid >> 7;
    float g[4];
#pragma unroll
    for (int q = 0; q < 4; ++q) {
      int gc = q * 128 + jj;
      g[q] = ((const float*)&part[gc])[b] + ((const float*)&part[512 + gc])[b] +
             ((const float*)&rres[gc])[b] + bs[gc];
    }
    float c = cst[b * 128 + jj];
    float cn = sigf(g[1]) * c + sigf(g[0]) * tanhf(g[2]);
    float hn = sigf(g[3]) * tanhf(cn);
    cst[b * 128 + jj] = cn;
    hst[b * 256 + hh * 128 + jj] = hn;
  }
}

__global__ __launch_bounds__(1024, 4) void lstm_decode_kernel(
    const float* __restrict__ emb, const float* __restrict__ Wout,
    const float* __restrict__ bout, const int* __restrict__ sosp,
    const int* __restrict__ eosp, float* __restrict__ ws,
    unsigned long long* __restrict__ key2, unsigned* __restrict__ flags,
    int* __restrict__ out) {
  const int tid = threadIdx.x;
  const int blk = blockIdx.x;
  __shared__ Smem sm;
  const int eos = *eosp;
  const int sos = *sosp;
  float4* h0b4 = (float4*)(ws + OFF_H0BUF);
  float4* h1b4 = (float4*)(ws + OFF_H1BUF);

  if (blk < NCELL) {
    // ======================= CELL block =======================
    const int bg = blk >> 1, hh = blk & 1, ph = 1 - hh;
    const float4* W0 = (const float4*)(ws + OFF_W0T) + (size_t)hh * 128 * 512;
    const float4* W1 = (const float4*)(ws + OFF_W1T) + (size_t)hh * 64 * 512;
    const float4* WH0 = (const float4*)(ws + OFF_WH0T) + (size_t)hh * 64 * 512;
    const float4* WH1 = (const float4*)(ws + OFF_WH1T) + (size_t)hh * 64 * 512;
    const float* bs0 = ws + OFF_BS0 + hh * 512;
    const float* bs1 = ws + OFF_BS1 + hh * 512;

    // t=0 state seed
    {
      int b = tid >> 8, k = tid & 255;
      float hv = ws[OFF_HINIT + (bg * 4 + b) * 256 + k];
      sm.c.h0[b * 256 + k] = hv;
      sm.c.h1[b * 256 + k] = hv;
    }
    if (tid < 512) {
      int b = tid >> 7, jj = tid & 127;
      float cv = ws[OFF_CINIT + (bg * 4 + b) * 256 + hh * 128 + jj];
      sm.c.c0[b * 128 + jj] = cv;
      sm.c.c1[b * 128 + jj] = cv;
    }
    if (tid < 4) sm.c.tok[tid] = sos;
    if (tid == 0) { sm.c.done4 = 0; sm.c.alldone = 0; }
    __syncthreads();
    // seed R0res/R1res from init states
    gemv_two<32>(WH0, sm.c.h0, 256, sm.c.part, tid);
    __syncthreads();
    if (tid < 512) sm.c.r0res[tid] = f4add(sm.c.part[tid], sm.c.part[512 + tid]);
    __syncthreads();
    gemv_two<32>(WH1, sm.c.h1, 256, sm.c.part, tid);
    __syncthreads();
    if (tid < 512) sm.c.r1res[tid] = f4add(sm.c.part[tid], sm.c.part[512 + tid]);
    __syncthreads();

    for (int t = 0; t < TSTEPS; ++t) {
      const unsigned T = (unsigned)(t + 1);
      // ---- E = Wih0(half) @ emb[tok] ----
      if (tid < 512) {
        int b = tid >> 7, j = tid & 127;
        ((float4*)sm.c.x)[b * 128 + j] = ((const float4*)emb)[(size_t)sm.c.tok[b] * 128 + j];
      }
      __syncthreads();
      gemv_two<64>(W0, sm.c.x, 512, sm.c.part, tid);
      __syncthreads();
      cellfold(sm.c.part, sm.c.r0res, bs0, sm.c.c0, sm.c.h0, hh, tid);
      __syncthreads();
      // post own h0 half, exchange with partner
      if (tid < 128) {
        int b = tid >> 5, j = tid & 31;
        float4 v = *(float4*)&sm.c.h0[b * 256 + hh * 128 + j * 4];
        stg_coh_f4(h0b4 + (bg * 4 + b) * 64 + hh * 32 + j, v);
      }
      drain_vm();
      __syncthreads();
      if (tid == 0) {
        st_cohu(flags + FL_H0F + blk * FSTR, T);
        while (ld_cohu(flags + FL_H0F + (blk ^ 1) * FSTR) < T) __builtin_amdgcn_s_sleep(1);
      }
      __syncthreads();
      if (tid < 128) {
        int b = tid >> 5, j = tid & 31;
        float4 v = ldg_coh_f4(h0b4 + (bg * 4 + b) * 64 + ph * 32 + j);
        *(float4*)&sm.c.h0[b * 256 + ph * 128 + j * 4] = v;
      }
      __syncthreads();
      // ---- G1 = Wih1(half) @ h0 ----
      gemv_two<32>(W1, sm.c.h0, 256, sm.c.part, tid);
      __syncthreads();
      cellfold(sm.c.part, sm.c.r1res, bs1, sm.c.c1, sm.c.h1, hh, tid);
      __syncthreads();
      // post h1 half + flag; relay all-ready to D
      if (tid < 128) {
        int b = tid >> 5, j = tid & 31;
        float4 v = *(float4*)&sm.c.h1[b * 256 + hh * 128 + j * 4];
        stg_coh_f4(h1b4 + (bg * 4 + b) * 64 + hh * 32 + j, v);
      }
      drain_vm();
      __syncthreads();
      if (tid == 0) st_cohu(flags + FL_H1C + blk * FSTR, T);
      if (tid < 64) {
        unsigned v = T;
        for (;;) {
          if (tid < 32) v = ld_cohu(flags + FL_H1C + tid * FSTR);
          if (__all((int)(v >= T))) break;
          __builtin_amdgcn_s_sleep(1);
        }
      }
      __syncthreads();
      if (tid == 0) st_cohu(flags + FL_H1ALL + blk * FSTR, T);
      // read partner h1 half (for R1)
      if (tid < 128) {
        int b = tid >> 5, j = tid & 31;
        float4 v = ldg_coh_f4(h1b4 + (bg * 4 + b) * 64 + ph * 32 + j);
        *(float4*)&sm.c.h1[b * 256 + ph * 128 + j * 4] = v;
      }
      __syncthreads();
      // ---- off-path: masks from step t-1 (for alldone) ----
      if (t > 0) {
        if (tid < 64) {
          unsigned tgt = (unsigned)t << 8;
          unsigned got = tgt;
          for (;;) {
            if (tid < 32) got = ld_cohu(flags + FL_TOK + tid * FSTR);
            if (__all((int)(got >= tgt))) break;
            __builtin_amdgcn_s_sleep(2);
          }
          if (tid < 32) sm.c.fm[tid] = got & 0xFFu;
        }
        __syncthreads();
        if (tid < 64) {
          int ok = 1;
          if (tid < 32) ok = (sm.c.fm[tid] == 0xFu);
          int all = __all(ok);
          if (tid == 0) sm.c.alldone = all;
        }
        __syncthreads();
      }
      // ---- off-path: R0/R1 for next step ----
      gemv_two<32>(WH0, sm.c.h0, 256, sm.c.part, tid);
      __syncthreads();
      if (tid < 512) sm.c.r0res[tid] = f4add(sm.c.part[tid], sm.c.part[512 + tid]);
      __syncthreads();
      gemv_two<32>(WH1, sm.c.h1, 256, sm.c.part, tid);
      __syncthreads();
      if (tid < 512) sm.c.r1res[tid] = f4add(sm.c.part[tid], sm.c.part[512 + tid]);
      __syncthreads();
      // ---- D-completion mirror ----
      if (tid < 64) {
        unsigned v = T;
        for (;;) {
          if (tid < 7) v = ld_cohu(flags + FL_DFLAG + (blk * 7 + tid) * FSTR);
          if (__all((int)(v >= T))) break;
          __builtin_amdgcn_s_sleep(4);
        }
      }
      __syncthreads();
      if (tid == 0) st_cohu(flags + FL_DMIR + blk * FSTR, T);
      if (tid < 64) {
        unsigned v = T;
        for (;;) {
          if (tid < 32) v = ld_cohu(flags + FL_DMIR + tid * FSTR);
          if (__all((int)(v >= T))) break;
          __builtin_amdgcn_s_sleep(2);
        }
      }
      __syncthreads();
      // ---- argmax fold for own 4 batches ----
      {
        int bb = tid >> 8, i = tid & 255;
        unsigned long long k = ld_coh64(key2 + (size_t)(bg * 4 + bb) * 256 + i);
        k = wmax64(k);
        if ((tid & 63) == 0) sm.c.fred[tid >> 6] = k;
      }
      __syncthreads();
      if (tid < 4) {
        int bb = tid;
        unsigned long long m = u64max(u64max(sm.c.fred[bb * 4], sm.c.fred[bb * 4 + 1]),
                                      u64max(sm.c.fred[bb * 4 + 2], sm.c.fred[bb * 4 + 3]));
        int v = (int)(~(unsigned)m);
        int outv = sm.c.alldone ? 0 : v;
        out[(bg * 4 + bb) * TSTEPS + t] = outv;
        int nd = ((sm.c.done4 >> bb) & 1) | (outv == eos ? 1 : 0);
        sm.c.tok[bb] = outv;
        sm.c.fm[bb] = (unsigned)nd;
      }
      __syncthreads();
      if (tid == 0) {
        int mask = (int)(sm.c.fm[0] | (sm.c.fm[1] << 1) | (sm.c.fm[2] << 2) | (sm.c.fm[3] << 3));
        sm.c.done4 = mask;
        if (t < TSTEPS - 1)
          st_cohu(flags + FL_TOK + blk * FSTR, ((unsigned)(t + 1) << 8) | (unsigned)mask);
      }
      __syncthreads();
    }
  } else {
    // ======================= D (logits) block =======================
    // Re-tiled: thread = (v 0..63 row-slot, bq 0..15 batch-quad).
    // Rows {v, 64+v} + epi row {128+v if v<nep}; batches bq*4..bq*4+3.
    // Per wave per k4: ~3 w-issues (each 1KB unique) + 4 h-broadcasts
    // (vs 1 + 8 before) -> ~22% fewer LDS issues in the dominant loop.
    const int d = blk - NCELL;
    const int r0 = (d * 32000) / ND, r1 = ((d + 1) * 32000) / ND;
    const int rows = r1 - r0, nep = rows - 128;  // 14 or 15
    const int v = tid & 63, bq = tid >> 6;
    const float4* Wout4 = (const float4*)Wout;
    const int nq = 144 * 16;

    const float bbA = bout[r0 + v];
    const float bbB = bout[r0 + 64 + v];
    const float bbE = (v < nep) ? bout[r0 + 128 + v] : 0.f;

    for (int t = 0; t < TSTEPS; ++t) {
      const unsigned T = (unsigned)(t + 1);
      // prefetch kc=0 Wout chunk (token-independent, streaming/nt)
      float4 wpre[3];
#pragma unroll
      for (int p = 0; p < 3; ++p) {
        int e = tid + p * 1024;
        if (e < nq) {
          int j = e / 144, r = e - j * 144;
          int rc = r0 + r; if (rc > 31999) rc = 31999;
          wpre[p] = ldnt_f4(Wout4 + (size_t)rc * 64 + j);
        } else wpre[p] = make_float4(0.f, 0.f, 0.f, 0.f);
      }
      // wait h1 ready (mirror line, 7 readers each)
      if (tid == 0) {
        while (ld_cohu(flags + FL_H1ALL + (d & 31) * FSTR) < T) __builtin_amdgcn_s_sleep(4);
      }
      __syncthreads();
      // read full h1 into registers (4 x 16B batched coherent loads)
      float4 hpre[4];
      {
        int b = tid >> 4, j = tid & 15;
        const float4* hp = (const float4*)h1b4 + (size_t)b * 64 + j;
        ldg_coh_f4x4(hp, hp + 16, hp + 32, hp + 48, hpre[0], hpre[1], hpre[2], hpre[3]);
      }
      float accA[4], accB[4], eacc[4];
#pragma unroll
      for (int i = 0; i < 4; ++i) { accA[i] = 0.f; accB[i] = 0.f; eacc[i] = 0.f; }

      for (int kc = 0; kc < 4; ++kc) {
        __syncthreads();
#pragma unroll
        for (int p = 0; p < 3; ++p) {
          int e = tid + p * 1024;
          if (e < nq) {
            int j = e / 144, r = e - j * 144;
            *(float4*)&sm.d.w[(j * 144 + r) * 4] = wpre[p];
          }
        }
        {
          int b = tid >> 4, j = tid & 15;
          *(float4*)&sm.d.h[b * 68 + j * 4] = hpre[kc];
        }
        __syncthreads();
        if (kc < 3) {
#pragma unroll
          for (int p = 0; p < 3; ++p) {
            int e = tid + p * 1024;
            if (e < nq) {
              int j = e / 144, r = e - j * 144;
              int rc = r0 + r; if (rc > 31999) rc = 31999;
              wpre[p] = ldnt_f4(Wout4 + (size_t)rc * 64 + (kc + 1) * 16 + j);
            }
          }
        }
        // main: rows {v, 64+v} (+epi 128+v), 4 batches
#pragma unroll 4
        for (int k4 = 0; k4 < 16; ++k4) {
          float4 wA = *(const float4*)&sm.d.w[(k4 * 144 + v) * 4];
          float4 wB = *(const float4*)&sm.d.w[(k4 * 144 + 64 + v) * 4];
          float4 wE = make_float4(0.f, 0.f, 0.f, 0.f);
          if (v < nep) wE = *(const float4*)&sm.d.w[(k4 * 144 + 128 + v) * 4];
#pragma unroll
          for (int bi = 0; bi < 4; ++bi) {
            float4 h4 = *(const float4*)&sm.d.h[(bq * 4 + bi) * 68 + k4 * 4];
            accA[bi] = fmaf(wA.x, h4.x, fmaf(wA.y, h4.y, fmaf(wA.z, h4.z, fmaf(wA.w, h4.w, accA[bi]))));
            accB[bi] = fmaf(wB.x, h4.x, fmaf(wB.y, h4.y, fmaf(wB.z, h4.z, fmaf(wB.w, h4.w, accB[bi]))));
            eacc[bi] = fmaf(wE.x, h4.x, fmaf(wE.y, h4.y, fmaf(wE.z, h4.z, fmaf(wE.w, h4.w, eacc[bi]))));
          }
        }
      }
      // ---- keys: per-batch fold over this wave's rows (full 144 coverage) ----
#pragma unroll
      for (int bi = 0; bi < 4; ++bi) {
        unsigned long long k = packkey(accA[bi] + bbA, r0 + v);
        k = u64max(k, packkey(accB[bi] + bbB, r0 + 64 + v));
        if (v < nep) k = u64max(k, packkey(eacc[bi] + bbE, r0 + 128 + v));
        k = wmax64(k);
        if (v == 0) sm.d.kr[bq * 4 + bi] = k;
      }
      __syncthreads();
      if (tid < 64) st_coh64(key2 + (size_t)tid * 256 + d, sm.d.kr[tid]);
      drain_vm();
      __syncthreads();
      if (tid == 0) st_cohu(flags + FL_DFLAG + d * FSTR, T);
    }
  }
}

extern "C" void kernel_launch(void* const* d_in, const int* in_sizes, int n_in,
                              void* d_out, int out_size, void* d_ws, size_t ws_size,
                              hipStream_t stream) {
  const float* enc  = (const float*)d_in[0];
  const float* emb  = (const float*)d_in[1];
  const float* Wh   = (const float*)d_in[2];
  const float* bh   = (const float*)d_in[3];
  const float* Wc   = (const float*)d_in[4];
  const float* bc   = (const float*)d_in[5];
  const float* Wih0 = (const float*)d_in[6];
  const float* Whh0 = (const float*)d_in[7];
  const float* bih0 = (const float*)d_in[8];
  const float* bhh0 = (const float*)d_in[9];
  const float* Wih1 = (const float*)d_in[10];
  const float* Whh1 = (const float*)d_in[11];
  const float* bih1 = (const float*)d_in[12];
  const float* bhh1 = (const float*)d_in[13];
  const float* Wout = (const float*)d_in[14];
  const float* bout = (const float*)d_in[15];
  const int* sosp   = (const int*)d_in[16];
  const int* eosp   = (const int*)d_in[17];

  float* ws = (float*)d_ws;
  char* base = (char*)d_ws + (size_t)OFF_FLOAT_END * 4;
  unsigned long long* key2 = (unsigned long long*)base;            // 131072 B
  unsigned* flags          = (unsigned*)(base + 131072);           // 49152 B
  int* out = (int*)d_out;

  lstm_init_kernel<<<80, 256, 0, stream>>>(enc, Wh, bh, Wc, bc, bih0, bhh0,
                                           bih1, bhh1, ws, key2, flags);
  lstm_relayout_kernel<<<256, 256, 0, stream>>>(Wih0, Whh0, Wih1, Whh1, ws);
  lstm_decode_kernel<<<NBLK, 1024, 0, stream>>>(emb, Wout, bout, sosp, eosp,
                                                ws, key2, flags, out);
}

// Round 5
// 3375.415 us; speedup vs baseline: 1.5041x; 1.5041x over previous
//
#include <hip/hip_runtime.h>
#include <math.h>

#define TSTEPS 48
#define NCELL 32
#define ND 224
#define NBLK (NCELL + ND)

// ---------------- ws float offsets ----------------
#define OFF_W0T   0            // [2 hh][128 k4][512 gc] float4 (Wih0 re-layout)
#define OFF_W1T   524288       // [2][64][512] float4 (Wih1)
#define OFF_WH0T  786432       // [2][64][512] float4 (Whh0)
#define OFF_WH1T  1048576      // [2][64][512] float4 (Whh1)
#define OFF_BS0   1310720      // [2 hh][512 gc]
#define OFF_BS1   1311744
#define OFF_HINIT 1312768      // [64][256]
#define OFF_CINIT 1329152
#define OFF_H0BUF 1345536      // [64][256]
#define OFF_H1BUF 1361920
#define OFF_FLOAT_END 1378304
// then: key2 u64[64][256] (131072 B), flags u32[12288] (49152 B)

#define FSTR 32
#define FL_H0F   0       // 32
#define FL_H1C   1024    // 32
#define FL_H1ALL 2048    // 32 (unused since r5: D polls H1C directly)
#define FL_DFLAG 3072    // 224
#define FL_DMIR  10240   // 32
#define FL_TOK   11264   // 32
#define NFLAGU32 12288

typedef float f4v __attribute__((ext_vector_type(4)));

// ---- coherent accessors ----
__device__ __forceinline__ unsigned ld_cohu(const unsigned* p) {
  return __hip_atomic_load((unsigned*)p, __ATOMIC_RELAXED, __HIP_MEMORY_SCOPE_AGENT);
}
__device__ __forceinline__ void st_cohu(unsigned* p, unsigned v) {
  __hip_atomic_store(p, v, __ATOMIC_RELAXED, __HIP_MEMORY_SCOPE_AGENT);
}
__device__ __forceinline__ unsigned long long ld_coh64(const unsigned long long* p) {
  return __hip_atomic_load((unsigned long long*)p, __ATOMIC_RELAXED, __HIP_MEMORY_SCOPE_AGENT);
}
__device__ __forceinline__ void st_coh64(unsigned long long* p, unsigned long long v) {
  __hip_atomic_store(p, v, __ATOMIC_RELAXED, __HIP_MEMORY_SCOPE_AGENT);
}
// 16B coherent load (bypass L0+L2 -> IC), blocking
__device__ __forceinline__ float4 ldg_coh_f4(const float4* p) {
  f4v r;
  asm volatile("global_load_dwordx4 %0, %1, off sc0 sc1\n\ts_waitcnt vmcnt(0)"
               : "=v"(r) : "v"(p) : "memory");
  return make_float4(r.x, r.y, r.z, r.w);
}
// 4 x 16B coherent loads in flight, one wait
__device__ __forceinline__ void ldg_coh_f4x4(const float4* p0, const float4* p1,
                                             const float4* p2, const float4* p3,
                                             float4& a, float4& b, float4& c, float4& d) {
  f4v ra, rb, rc, rd;
  asm volatile(
      "global_load_dwordx4 %0, %4, off sc0 sc1\n\t"
      "global_load_dwordx4 %1, %5, off sc0 sc1\n\t"
      "global_load_dwordx4 %2, %6, off sc0 sc1\n\t"
      "global_load_dwordx4 %3, %7, off sc0 sc1\n\t"
      "s_waitcnt vmcnt(0)"
      : "=&v"(ra), "=&v"(rb), "=&v"(rc), "=&v"(rd)
      : "v"(p0), "v"(p1), "v"(p2), "v"(p3) : "memory");
  a = make_float4(ra.x, ra.y, ra.z, ra.w);
  b = make_float4(rb.x, rb.y, rb.z, rb.w);
  c = make_float4(rc.x, rc.y, rc.z, rc.w);
  d = make_float4(rd.x, rd.y, rd.z, rd.w);
}
// 16B coherent write-through store (fire and forget; drain_vm before flag post)
__device__ __forceinline__ void stg_coh_f4(float4* p, float4 v) {
  f4v t = {v.x, v.y, v.z, v.w};
  asm volatile("global_store_dwordx4 %0, %1, off sc0 sc1" :: "v"(p), "v"(t) : "memory");
}
__device__ __forceinline__ void drain_vm() {
  asm volatile("s_waitcnt vmcnt(0)" ::: "memory");
}
// non-temporal 16B load (streaming; don't pollute L2 — protects cell weights in L2)
__device__ __forceinline__ float4 ldnt_f4(const float4* p) {
  f4v v = __builtin_nontemporal_load((const f4v*)p);
  return make_float4(v.x, v.y, v.z, v.w);
}
__device__ __forceinline__ float sigf(float x) { return 1.0f / (1.0f + expf(-x)); }
__device__ __forceinline__ unsigned long long u64max(unsigned long long a, unsigned long long b) {
  return a > b ? a : b;
}
__device__ __forceinline__ unsigned long long wmax64(unsigned long long k) {
#pragma unroll
  for (int off = 1; off < 64; off <<= 1) {
    unsigned long long o = __shfl_xor(k, off, 64);
    k = u64max(k, o);
  }
  return k;
}
__device__ __forceinline__ unsigned long long packkey(float lg, int v) {
  unsigned u = __float_as_uint(lg);
  u = (u & 0x80000000u) ? ~u : (u | 0x80000000u);
  return ((unsigned long long)u << 32) | (unsigned)(~(unsigned)v);
}
__device__ __forceinline__ float4 f4add(float4 a, float4 b) {
  return make_float4(a.x + b.x, a.y + b.y, a.z + b.z, a.w + b.w);
}

// ---------------- init kernels ----------------
__global__ void lstm_init_kernel(const float* enc, const float* Wh, const float* bh,
                                 const float* Wc, const float* bc,
                                 const float* bih0, const float* bhh0,
                                 const float* bih1, const float* bhh1,
                                 float* ws, unsigned long long* key2, unsigned* flags) {
  const int tid = threadIdx.x, blk = blockIdx.x;
  if (blk < 64) {
    __shared__ float el[256];
    el[tid] = enc[blk * 256 + tid];
    __syncthreads();
    const float4* el4 = (const float4*)el;
    const float4* wh4 = (const float4*)(Wh + tid * 256);
    const float4* wc4 = (const float4*)(Wc + tid * 256);
    float ah = bh[tid], ac = bc[tid];
#pragma unroll 4
    for (int f = 0; f < 64; ++f) {
      float4 x = el4[f], a = wh4[f], b = wc4[f];
      ah = fmaf(a.x, x.x, fmaf(a.y, x.y, fmaf(a.z, x.z, fmaf(a.w, x.w, ah))));
      ac = fmaf(b.x, x.x, fmaf(b.y, x.y, fmaf(b.z, x.z, fmaf(b.w, x.w, ac))));
    }
    ws[OFF_HINIT + blk * 256 + tid] = ah;
    ws[OFF_CINIT + blk * 256 + tid] = ac;
  } else if (blk == 64) {
    for (int g = tid; g < 1024; g += 256) {
      int hh = g >> 9, gc = g & 511;
      int row = (gc >> 7) * 256 + hh * 128 + (gc & 127);
      ws[OFF_BS0 + g] = bih0[row] + bhh0[row];
      ws[OFF_BS1 + g] = bih1[row] + bhh1[row];
    }
  } else {
    const int base = (blk - 65) * 256 + tid;  // 15 blocks, stride 3840
    for (int i = base; i < 64 * 256; i += 15 * 256) key2[i] = 0ull;
    for (int i = base; i < NFLAGU32; i += 15 * 256) flags[i] = 0u;
  }
}

// re-layout the 4 gate-weight matrices into [hh][k4][512 gc] float4
__global__ void lstm_relayout_kernel(const float* Wih0, const float* Whh0,
                                     const float* Wih1, const float* Whh1, float* ws) {
  const int gid = blockIdx.x * 256 + threadIdx.x;
  const int gstr = 256 * 256;
  const float* srcs[4] = {Wih0, Wih1, Whh0, Whh1};
  const int dsts[4] = {OFF_W0T, OFF_W1T, OFF_WH0T, OFF_WH1T};
  const int k4tot[4] = {128, 64, 64, 64};
  for (int s = 0; s < 4; ++s) {
    const int n = 2 * k4tot[s] * 512;
    float4* dst = (float4*)(ws + dsts[s]);
    const float4* src = (const float4*)srcs[s];
    for (int e = gid; e < n; e += gstr) {
      int hh = e / (k4tot[s] * 512);
      int r = e - hh * k4tot[s] * 512;
      int k4 = r / 512, gc = r - k4 * 512;
      int row = (gc >> 7) * 256 + hh * 128 + (gc & 127);
      dst[e] = src[(size_t)row * k4tot[s] + k4];
    }
  }
}

// ---------------- decode: shared-memory layouts ----------------
struct CellSm {
  float x[4 * 512];
  float4 part[1024];
  float4 r0res[512];
  float4 r1res[512];
  float h0[4 * 256];
  float h1[4 * 256];
  float c0[4 * 128];
  float c1[4 * 128];
  int tok[4];
  unsigned fm[32];
  unsigned long long fred[16];
  int done4;
  int alldone;
};
struct DSm {
  float w[16 * 144 * 4];        // [k4][144 rows][4]
  float h[64 * 68];             // [b][68] (padded, 16B-aligned rows)
  unsigned long long kr[128];   // [b][wavehalf]
  unsigned long long epi[16 * 64];
};
union Smem { CellSm c; DSm d; };

// GEMV half: thread (gc = tid&511, kh = tid>>9) accumulates its K-half for 4 batches.
template <int K4H>
__device__ __forceinline__ void gemv_half(const float4* __restrict__ W,
                                          const float* __restrict__ xl, int xstride,
                                          float4* __restrict__ part, int tid) {
  const int kh = tid >> 9;
  float a0 = 0.f, a1 = 0.f, a2 = 0.f, a3 = 0.f;
  const float4* wp = W + (size_t)(kh * K4H) * 512 + (tid & 511);
  const float* x0 = xl + kh * K4H * 4;
#pragma unroll 8
  for (int i = 0; i < K4H; ++i) {
    float4 w = wp[(size_t)i * 512];
    float4 xa = *(const float4*)(x0 + i * 4);
    float4 xb = *(const float4*)(x0 + xstride + i * 4);
    float4 xc = *(const float4*)(x0 + 2 * xstride + i * 4);
    float4 xd = *(const float4*)(x0 + 3 * xstride + i * 4);
    a0 = fmaf(w.x, xa.x, fmaf(w.y, xa.y, fmaf(w.z, xa.z, fmaf(w.w, xa.w, a0))));
    a1 = fmaf(w.x, xb.x, fmaf(w.y, xb.y, fmaf(w.z, xb.z, fmaf(w.w, xb.w, a1))));
    a2 = fmaf(w.x, xc.x, fmaf(w.y, xc.y, fmaf(w.z, xc.z, fmaf(w.w, xc.w, a2))));
    a3 = fmaf(w.x, xd.x, fmaf(w.y, xd.y, fmaf(w.z, xd.z, fmaf(w.w, xd.w, a3))));
  }
  part[tid] = make_float4(a0, a1, a2, a3);
}

__device__ __forceinline__ void cellfold(const float4* part, const float4* rres,
                                         const float* bs, float* cst, float* hst,
                                         int hh, int tid) {
  if (tid < 512) {
    int jj = tid & 127, b = tid >> 7;
    float g[4];
#pragma unroll
    for (int q = 0; q < 4; ++q) {
      int gc = q * 128 + jj;
      g[q] = ((const float*)&part[gc])[b] + ((const float*)&part[512 + gc])[b] +
             ((const float*)&rres[gc])[b] + bs[gc];
    }
    float c = cst[b * 128 + jj];
    float cn = sigf(g[1]) * c + sigf(g[0]) * tanhf(g[2]);
    float hn = sigf(g[3]) * tanhf(cn);
    cst[b * 128 + jj] = cn;
    hst[b * 256 + hh * 128 + jj] = hn;
  }
}

__global__ __launch_bounds__(1024, 4) void lstm_decode_kernel(
    const float* __restrict__ emb, const float* __restrict__ Wout,
    const float* __restrict__ bout, const int* __restrict__ sosp,
    const int* __restrict__ eosp, float* __restrict__ ws,
    unsigned long long* __restrict__ key2, unsigned* __restrict__ flags,
    int* __restrict__ out) {
  const int tid = threadIdx.x;
  const int blk = blockIdx.x;
  __shared__ Smem sm;
  const int eos = *eosp;
  const int sos = *sosp;
  float4* h0b4 = (float4*)(ws + OFF_H0BUF);
  float4* h1b4 = (float4*)(ws + OFF_H1BUF);

  if (blk < NCELL) {
    // ======================= CELL block =======================
    const int bg = blk >> 1, hh = blk & 1, ph = 1 - hh;
    const float4* W0 = (const float4*)(ws + OFF_W0T) + (size_t)hh * 128 * 512;
    const float4* W1 = (const float4*)(ws + OFF_W1T) + (size_t)hh * 64 * 512;
    const float4* WH0 = (const float4*)(ws + OFF_WH0T) + (size_t)hh * 64 * 512;
    const float4* WH1 = (const float4*)(ws + OFF_WH1T) + (size_t)hh * 64 * 512;
    const float* bs0 = ws + OFF_BS0 + hh * 512;
    const float* bs1 = ws + OFF_BS1 + hh * 512;

    // t=0 state seed
    {
      int b = tid >> 8, k = tid & 255;
      float hv = ws[OFF_HINIT + (bg * 4 + b) * 256 + k];
      sm.c.h0[b * 256 + k] = hv;
      sm.c.h1[b * 256 + k] = hv;
    }
    if (tid < 512) {
      int b = tid >> 7, jj = tid & 127;
      float cv = ws[OFF_CINIT + (bg * 4 + b) * 256 + hh * 128 + jj];
      sm.c.c0[b * 128 + jj] = cv;
      sm.c.c1[b * 128 + jj] = cv;
    }
    if (tid < 4) sm.c.tok[tid] = sos;
    if (tid == 0) { sm.c.done4 = 0; sm.c.alldone = 0; }
    __syncthreads();
    // seed R0res/R1res from init states
    gemv_half<32>(WH0, sm.c.h0, 256, sm.c.part, tid);
    __syncthreads();
    if (tid < 512) sm.c.r0res[tid] = f4add(sm.c.part[tid], sm.c.part[512 + tid]);
    __syncthreads();
    gemv_half<32>(WH1, sm.c.h1, 256, sm.c.part, tid);
    __syncthreads();
    if (tid < 512) sm.c.r1res[tid] = f4add(sm.c.part[tid], sm.c.part[512 + tid]);
    __syncthreads();

    for (int t = 0; t < TSTEPS; ++t) {
      const unsigned T = (unsigned)(t + 1);
      // ---- E = Wih0(half) @ emb[tok] ----
      if (tid < 512) {
        int b = tid >> 7, j = tid & 127;
        ((float4*)sm.c.x)[b * 128 + j] = ((const float4*)emb)[(size_t)sm.c.tok[b] * 128 + j];
      }
      __syncthreads();
      gemv_half<64>(W0, sm.c.x, 512, sm.c.part, tid);
      __syncthreads();
      cellfold(sm.c.part, sm.c.r0res, bs0, sm.c.c0, sm.c.h0, hh, tid);
      __syncthreads();
      // post own h0 half, exchange with partner
      if (tid < 128) {
        int b = tid >> 5, j = tid & 31;
        float4 v = *(float4*)&sm.c.h0[b * 256 + hh * 128 + j * 4];
        stg_coh_f4(h0b4 + (bg * 4 + b) * 64 + hh * 32 + j, v);
      }
      drain_vm();
      __syncthreads();
      if (tid == 0) {
        st_cohu(flags + FL_H0F + blk * FSTR, T);
        while (ld_cohu(flags + FL_H0F + (blk ^ 1) * FSTR) < T) __builtin_amdgcn_s_sleep(1);
      }
      __syncthreads();
      if (tid < 128) {
        int b = tid >> 5, j = tid & 31;
        float4 v = ldg_coh_f4(h0b4 + (bg * 4 + b) * 64 + ph * 32 + j);
        *(float4*)&sm.c.h0[b * 256 + ph * 128 + j * 4] = v;
      }
      __syncthreads();
      // ---- G1 = Wih1(half) @ h0 ----
      gemv_half<32>(W1, sm.c.h0, 256, sm.c.part, tid);
      __syncthreads();
      cellfold(sm.c.part, sm.c.r1res, bs1, sm.c.c1, sm.c.h1, hh, tid);
      __syncthreads();
      // post h1 half + flag; D blocks observe the 32 H1C flags directly (no relay).
      if (tid < 128) {
        int b = tid >> 5, j = tid & 31;
        float4 v = *(float4*)&sm.c.h1[b * 256 + hh * 128 + j * 4];
        stg_coh_f4(h1b4 + (bg * 4 + b) * 64 + hh * 32 + j, v);
      }
      drain_vm();
      __syncthreads();
      if (tid == 0) {
        st_cohu(flags + FL_H1C + blk * FSTR, T);
        // only the partner's half is needed locally (for R1)
        while (ld_cohu(flags + FL_H1C + (blk ^ 1) * FSTR) < T) __builtin_amdgcn_s_sleep(1);
      }
      __syncthreads();
      // read partner h1 half (for R1)
      if (tid < 128) {
        int b = tid >> 5, j = tid & 31;
        float4 v = ldg_coh_f4(h1b4 + (bg * 4 + b) * 64 + ph * 32 + j);
        *(float4*)&sm.c.h1[b * 256 + ph * 128 + j * 4] = v;
      }
      __syncthreads();
      // ---- off-path: masks from step t-1 (for alldone) ----
      if (t > 0) {
        if (tid < 64) {
          unsigned tgt = (unsigned)t << 8;
          unsigned got = tgt;
          for (;;) {
            if (tid < 32) got = ld_cohu(flags + FL_TOK + tid * FSTR);
            if (__all((int)(got >= tgt))) break;
            __builtin_amdgcn_s_sleep(2);
          }
          if (tid < 32) sm.c.fm[tid] = got & 0xFFu;
        }
        __syncthreads();
        if (tid < 64) {
          int ok = 1;
          if (tid < 32) ok = (sm.c.fm[tid] == 0xFu);
          int all = __all(ok);
          if (tid == 0) sm.c.alldone = all;
        }
        __syncthreads();
      }
      // ---- off-path: R0/R1 for next step ----
      gemv_half<32>(WH0, sm.c.h0, 256, sm.c.part, tid);
      __syncthreads();
      if (tid < 512) sm.c.r0res[tid] = f4add(sm.c.part[tid], sm.c.part[512 + tid]);
      __syncthreads();
      gemv_half<32>(WH1, sm.c.h1, 256, sm.c.part, tid);
      __syncthreads();
      if (tid < 512) sm.c.r1res[tid] = f4add(sm.c.part[tid], sm.c.part[512 + tid]);
      __syncthreads();
      // ---- D-completion mirror ----
      if (tid < 64) {
        unsigned v = T;
        for (;;) {
          if (tid < 7) v = ld_cohu(flags + FL_DFLAG + (blk * 7 + tid) * FSTR);
          if (__all((int)(v >= T))) break;
          __builtin_amdgcn_s_sleep(4);
        }
      }
      __syncthreads();
      if (tid == 0) st_cohu(flags + FL_DMIR + blk * FSTR, T);
      if (tid < 64) {
        unsigned v = T;
        for (;;) {
          if (tid < 32) v = ld_cohu(flags + FL_DMIR + tid * FSTR);
          if (__all((int)(v >= T))) break;
          __builtin_amdgcn_s_sleep(2);
        }
      }
      __syncthreads();
      // ---- argmax fold for own 4 batches ----
      {
        int bb = tid >> 8, i = tid & 255;
        unsigned long long k = ld_coh64(key2 + (size_t)(bg * 4 + bb) * 256 + i);
        k = wmax64(k);
        if ((tid & 63) == 0) sm.c.fred[tid >> 6] = k;
      }
      __syncthreads();
      if (tid < 4) {
        int bb = tid;
        unsigned long long m = u64max(u64max(sm.c.fred[bb * 4], sm.c.fred[bb * 4 + 1]),
                                      u64max(sm.c.fred[bb * 4 + 2], sm.c.fred[bb * 4 + 3]));
        int v = (int)(~(unsigned)m);
        int outv = sm.c.alldone ? 0 : v;
        out[(bg * 4 + bb) * TSTEPS + t] = outv;
        int nd = ((sm.c.done4 >> bb) & 1) | (outv == eos ? 1 : 0);
        sm.c.tok[bb] = outv;
        sm.c.fm[bb] = (unsigned)nd;
      }
      __syncthreads();
      if (tid == 0) {
        int mask = (int)(sm.c.fm[0] | (sm.c.fm[1] << 1) | (sm.c.fm[2] << 2) | (sm.c.fm[3] << 3));
        sm.c.done4 = mask;
        if (t < TSTEPS - 1)
          st_cohu(flags + FL_TOK + blk * FSTR, ((unsigned)(t + 1) << 8) | (unsigned)mask);
      }
      __syncthreads();
    }
  } else {
    // ======================= D (logits) block =======================
    const int d = blk - NCELL;
    const int r0 = (d * 32000) / ND, r1 = ((d + 1) * 32000) / ND;
    const int rows = r1 - r0, nep = rows - 128;  // 14 or 15
    const int bg = tid >> 7, v = tid & 127;
    const int erow = tid >> 6, eb = tid & 63;
    const float4* Wout4 = (const float4*)Wout;
    const int nq = 144 * 16;

    for (int t = 0; t < TSTEPS; ++t) {
      const unsigned T = (unsigned)(t + 1);
      // prefetch kc=0 Wout chunk (token-independent)
      float4 wpre[3];
#pragma unroll
      for (int p = 0; p < 3; ++p) {
        int e = tid + p * 1024;
        if (e < nq) {
          int j = e / 144, r = e - j * 144;
          int rc = r0 + r; if (rc > 31999) rc = 31999;
          wpre[p] = ldnt_f4(Wout4 + (size_t)rc * 64 + j);
        } else wpre[p] = make_float4(0.f, 0.f, 0.f, 0.f);
      }
      // EARLY-STAGE kc0 w into LDS (token-independent; prior step's end-barrier
      // ordered all reads of sm.d.w before this write) — overlaps the h1 wait.
#pragma unroll
      for (int p = 0; p < 3; ++p) {
        int e = tid + p * 1024;
        if (e < nq) {
          int j = e / 144, r = e - j * 144;
          *(float4*)&sm.d.w[(j * 144 + r) * 4] = wpre[p];
        }
      }
      // wait h1 ready: wave0 polls all 32 H1C flags directly (no cell relay)
      if (tid < 64) {
        unsigned hv = T;
        for (;;) {
          if (tid < 32) hv = ld_cohu(flags + FL_H1C + tid * FSTR);
          if (__all((int)(hv >= T))) break;
          __builtin_amdgcn_s_sleep(4);
        }
      }
      __syncthreads();
      // read full h1 into registers (4 x 16B batched coherent loads)
      float4 hpre[4];
      {
        int b = tid >> 4, j = tid & 15;
        const float4* hp = (const float4*)h1b4 + (size_t)b * 64 + j;
        ldg_coh_f4x4(hp, hp + 16, hp + 32, hp + 48, hpre[0], hpre[1], hpre[2], hpre[3]);
      }
      float acc[8];
#pragma unroll
      for (int i = 0; i < 8; ++i) acc[i] = 0.f;
      float eacc = 0.f;

      for (int kc = 0; kc < 4; ++kc) {
        if (kc > 0) {
          __syncthreads();
#pragma unroll
          for (int p = 0; p < 3; ++p) {
            int e = tid + p * 1024;
            if (e < nq) {
              int j = e / 144, r = e - j * 144;
              *(float4*)&sm.d.w[(j * 144 + r) * 4] = wpre[p];
            }
          }
        }
        {
          int b = tid >> 4, j = tid & 15;
          *(float4*)&sm.d.h[b * 68 + j * 4] = hpre[kc];
        }
        __syncthreads();
        if (kc < 3) {
#pragma unroll
          for (int p = 0; p < 3; ++p) {
            int e = tid + p * 1024;
            if (e < nq) {
              int j = e / 144, r = e - j * 144;
              int rc = r0 + r; if (rc > 31999) rc = 31999;
              wpre[p] = ldnt_f4(Wout4 + (size_t)rc * 64 + (kc + 1) * 16 + j);
            }
          }
        }
        // main: row = r0 + v, 8 batches
#pragma unroll 4
        for (int k4 = 0; k4 < 16; ++k4) {
          float4 w4 = *(const float4*)&sm.d.w[(k4 * 144 + v) * 4];
#pragma unroll
          for (int bi = 0; bi < 8; ++bi) {
            float4 h4 = *(const float4*)&sm.d.h[(bg * 8 + bi) * 68 + k4 * 4];
            acc[bi] = fmaf(w4.x, h4.x, fmaf(w4.y, h4.y, fmaf(w4.z, h4.z, fmaf(w4.w, h4.w, acc[bi]))));
          }
        }
        // epilogue rows 128..rows-1 (wave-uniform branch)
        if (erow < nep) {
#pragma unroll 4
          for (int k4 = 0; k4 < 16; ++k4) {
            float4 w4 = *(const float4*)&sm.d.w[(k4 * 144 + 128 + erow) * 4];
            float4 h4 = *(const float4*)&sm.d.h[eb * 68 + k4 * 4];
            eacc = fmaf(w4.x, h4.x, fmaf(w4.y, h4.y, fmaf(w4.z, h4.z, fmaf(w4.w, h4.w, eacc))));
          }
        }
      }
      // ---- keys + block reduce ----
      {
        float bb_ = bout[r0 + v];
#pragma unroll
        for (int bi = 0; bi < 8; ++bi) {
          unsigned long long k = packkey(acc[bi] + bb_, r0 + v);
          k = wmax64(k);
          if ((tid & 63) == 0) sm.d.kr[(bg * 8 + bi) * 2 + (v >> 6)] = k;
        }
      }
      if (erow < nep) {
        sm.d.epi[erow * 64 + eb] = packkey(eacc + bout[r0 + 128 + erow], r0 + 128 + erow);
      } else {
        sm.d.epi[erow * 64 + eb] = 0ull;
      }
      __syncthreads();
      if (tid < 64) {
        unsigned long long m = u64max(sm.d.kr[tid * 2], sm.d.kr[tid * 2 + 1]);
#pragma unroll
        for (int er = 0; er < 15; ++er) m = u64max(m, sm.d.epi[er * 64 + tid]);
        st_coh64(key2 + (size_t)tid * 256 + d, m);
      }
      drain_vm();
      __syncthreads();
      if (tid == 0) st_cohu(flags + FL_DFLAG + d * FSTR, T);
    }
  }
}

extern "C" void kernel_launch(void* const* d_in, const int* in_sizes, int n_in,
                              void* d_out, int out_size, void* d_ws, size_t ws_size,
                              hipStream_t stream) {
  const float* enc  = (const float*)d_in[0];
  const float* emb  = (const float*)d_in[1];
  const float* Wh   = (const float*)d_in[2];
  const float* bh   = (const float*)d_in[3];
  const float* Wc   = (const float*)d_in[4];
  const float* bc   = (const float*)d_in[5];
  const float* Wih0 = (const float*)d_in[6];
  const float* Whh0 = (const float*)d_in[7];
  const float* bih0 = (const float*)d_in[8];
  const float* bhh0 = (const float*)d_in[9];
  const float* Wih1 = (const float*)d_in[10];
  const float* Whh1 = (const float*)d_in[11];
  const float* bih1 = (const float*)d_in[12];
  const float* bhh1 = (const float*)d_in[13];
  const float* Wout = (const float*)d_in[14];
  const float* bout = (const float*)d_in[15];
  const int* sosp   = (const int*)d_in[16];
  const int* eosp   = (const int*)d_in[17];

  float* ws = (float*)d_ws;
  char* base = (char*)d_ws + (size_t)OFF_FLOAT_END * 4;
  unsigned long long* key2 = (unsigned long long*)base;            // 131072 B
  unsigned* flags          = (unsigned*)(base + 131072);           // 49152 B
  int* out = (int*)d_out;

  lstm_init_kernel<<<80, 256, 0, stream>>>(enc, Wh, bh, Wc, bc, bih0, bhh0,
                                           bih1, bhh1, ws, key2, flags);
  lstm_relayout_kernel<<<256, 256, 0, stream>>>(Wih0, Whh0, Wih1, Whh1, ws);
  lstm_decode_kernel<<<NBLK, 1024, 0, stream>>>(emb, Wout, bout, sosp, eosp,
                                                ws, key2, flags, out);
}